// Round 6
// baseline (282.958 us; speedup 1.0000x reference)
//
#include <hip/hip_runtime.h>
#include <hip/hip_bf16.h>

#define NN 100000
#define NE 800000
#define NG 2000
#define EMB 64
#define HID 128
#define NCLS 10

#define NBKT 196                       // coarse dst buckets (512 nodes each)
#define EPB 4096                       // edges per counting block
#define NBA ((NE + EPB - 1) / EPB)     // 196 counting blocks
#define NSCAN (NBKT * NBA)             // 38416
#define GS_NB ((NSCAN + 511) / 512)    // 76

typedef __attribute__((ext_vector_type(8))) short short8;
typedef __attribute__((ext_vector_type(4))) float f32x4;
typedef unsigned short u16;
typedef unsigned int u32;

// monotone float<->uint encoding so unsigned atomicMax == float max
static __device__ __forceinline__ unsigned fenc(float f) {
    unsigned u = __float_as_uint(f);
    return (u & 0x80000000u) ? ~u : (u | 0x80000000u);
}
static __device__ __forceinline__ float fdec(unsigned u) {
    return (u & 0x80000000u) ? __uint_as_float(u & 0x7FFFFFFFu) : __uint_as_float(~u);
}
static __device__ __forceinline__ u16 f2bf(float f) {
    u32 u = __float_as_uint(f);
    return (u16)((u + 0x7FFFu + ((u >> 16) & 1u)) >> 16);
}
static __device__ __forceinline__ float bfu(u16 v) {
    return __uint_as_float(((u32)v) << 16);
}

__global__ void k_init(unsigned* genc, float* relp, u16* Bt1, u16* Bt2,
                       const float* rel_table, const float* w1l, const float* w1r,
                       const float* w2l, const float* w2r) {
    int i = blockIdx.x * 256 + threadIdx.x;   // grid covers 256000
    if (i < NG * HID) genc[i] = 0x007FFFFFu;  // fenc(-inf)
    if (i < 3 * HID) {
        int t = i >> 7, j = i & 127;
        float s = 0.f;
        for (int k = 0; k < 16; ++k)
            s += rel_table[t * 16 + k] * w1l[(64 + k) * HID + j];
        relp[i] = s;
    }
    if (i < 128 * 128) {   // Bt1[c][k] = B1[k][c], B1 = [w1l[0:64]; w1r]
        int c = i >> 7, k = i & 127;
        float w = (k < 64) ? w1l[k * HID + c] : w1r[(k - 64) * HID + c];
        Bt1[c * 128 + k] = f2bf(w);
    }
    if (i < 128 * 256) {   // Bt2[c][k] = B2[k][c], B2 = [w2l; w2r]
        int c = i >> 8, k = i & 255;
        float w = (k < 128) ? w2l[k * HID + c] : w2r[(k - 128) * HID + c];
        Bt2[c * 256 + k] = f2bf(w);
    }
}

// embedding gather -> bf16 x [NN][64]; thread handles 2 features
__global__ void k_embed(const int* __restrict__ tok, const float* __restrict__ emb,
                        u32* __restrict__ xb) {
    int i = blockIdx.x * 256 + threadIdx.x;   // < NN*32
    int n = i >> 5, p = i & 31;
    float2 e = *(const float2*)&emb[tok[n] * EMB + p * 2];
    xb[i] = (u32)f2bf(e.x) | ((u32)f2bf(e.y) << 16);
}

// ---- atomic-free CSR build: two-level counting sort by dst ----

__global__ __launch_bounds__(256) void k_cnt(const int* __restrict__ dst,
                                             int* __restrict__ counts) {
    __shared__ int hist[NBKT];
    int t = threadIdx.x;
    for (int i = t; i < NBKT; i += 256) hist[i] = 0;
    __syncthreads();
    int base = blockIdx.x * EPB;
    for (int j = t; j < EPB; j += 256) {
        int e = base + j;
        if (e < NE) atomicAdd(&hist[dst[e] >> 9], 1);
    }
    __syncthreads();
    for (int i = t; i < NBKT; i += 256)
        counts[i * NBA + blockIdx.x] = hist[i];  // bucket-major for scan
}

__global__ __launch_bounds__(256) void k_gs1(const int* __restrict__ v, int* __restrict__ part) {
    __shared__ int ws[4];
    int t = threadIdx.x;
    int i0 = blockIdx.x * 512 + t * 2;
    int e0 = (i0 < NSCAN) ? v[i0] : 0;
    int e1 = (i0 + 1 < NSCAN) ? v[i0 + 1] : 0;
    int s = e0 + e1;
    for (int off = 32; off > 0; off >>= 1) s += __shfl_down(s, off, 64);
    if ((t & 63) == 0) ws[t >> 6] = s;
    __syncthreads();
    if (t == 0) part[blockIdx.x] = ws[0] + ws[1] + ws[2] + ws[3];
}

__global__ __launch_bounds__(128) void k_gs2(int* __restrict__ part) {
    __shared__ int s[128];
    int t = threadIdx.x;
    int v = (t < GS_NB) ? part[t] : 0;
    s[t] = v;
    __syncthreads();
    for (int off = 1; off < 128; off <<= 1) {
        int u = (t >= off) ? s[t - off] : 0;
        __syncthreads();
        s[t] += u;
        __syncthreads();
    }
    if (t < GS_NB) part[t] = s[t] - v;  // exclusive
}

__global__ __launch_bounds__(256) void k_gs3(const int* __restrict__ v,
                                             const int* __restrict__ part,
                                             int* __restrict__ out) {
    __shared__ int s[256];
    int t = threadIdx.x;
    int i0 = blockIdx.x * 512 + t * 2;
    int e0 = (i0 < NSCAN) ? v[i0] : 0;
    int e1 = (i0 + 1 < NSCAN) ? v[i0 + 1] : 0;
    int tsum = e0 + e1;
    s[t] = tsum;
    __syncthreads();
    for (int off = 1; off < 256; off <<= 1) {
        int u = (t >= off) ? s[t - off] : 0;
        __syncthreads();
        s[t] += u;
        __syncthreads();
    }
    int p0 = part[blockIdx.x] + s[t] - tsum;
    if (i0 < NSCAN) out[i0] = p0;
    if (i0 + 1 < NSCAN) out[i0 + 1] = p0 + e0;
}

// pack: src(17) | etype(2)<<17 | dstlow(9)<<19
__global__ __launch_bounds__(256) void k_part(const int* __restrict__ src,
                                              const int* __restrict__ dst,
                                              const int* __restrict__ et,
                                              const int* __restrict__ scanned,
                                              u32* __restrict__ coarse) {
    __shared__ int cur[NBKT];
    int t = threadIdx.x;
    for (int i = t; i < NBKT; i += 256) cur[i] = scanned[i * NBA + blockIdx.x];
    __syncthreads();
    int base = blockIdx.x * EPB;
    for (int j = t; j < EPB; j += 256) {
        int e = base + j;
        if (e < NE) {
            int d = dst[e];
            int pos = atomicAdd(&cur[d >> 9], 1);
            coarse[pos] = (u32)src[e] | ((u32)et[e] << 17) | ((u32)(d & 511) << 19);
        }
    }
}

__global__ __launch_bounds__(256) void k_csr(const int* __restrict__ scanned,
                                             const u32* __restrict__ coarse,
                                             int* __restrict__ offsets,
                                             int* __restrict__ packed) {
    __shared__ int hist[512];
    __shared__ int ex[512];
    __shared__ int ts[256];
    int b = blockIdx.x, t = threadIdx.x;
    int beg = scanned[b * NBA];
    int end = (b + 1 < NBKT) ? scanned[(b + 1) * NBA] : NE;
    hist[t] = 0; hist[t + 256] = 0;
    __syncthreads();
    for (int i = beg + t; i < end; i += 256)
        atomicAdd(&hist[(coarse[i] >> 19) & 511], 1);
    __syncthreads();
    int a0 = hist[2 * t], a1 = hist[2 * t + 1];
    int sum = a0 + a1;
    ts[t] = sum;
    __syncthreads();
    for (int off = 1; off < 256; off <<= 1) {
        int u = (t >= off) ? ts[t - off] : 0;
        __syncthreads();
        ts[t] += u;
        __syncthreads();
    }
    int ep = ts[t] - sum;
    ex[2 * t] = ep;
    ex[2 * t + 1] = ep + a0;
    __syncthreads();
    int node0 = b * 512;
    if (node0 + 2 * t < NN)     offsets[node0 + 2 * t]     = beg + ex[2 * t];
    if (node0 + 2 * t + 1 < NN) offsets[node0 + 2 * t + 1] = beg + ex[2 * t + 1];
    if (b == NBKT - 1 && t == 0) offsets[NN] = NE;
    hist[2 * t] = beg + ex[2 * t];
    hist[2 * t + 1] = beg + ex[2 * t + 1];
    __syncthreads();
    for (int i = beg + t; i < end; i += 256) {
        u32 pk = coarse[i];
        int pos = atomicAdd(&hist[(pk >> 19) & 511], 1);
        packed[pos] = (int)(pk & 0x1FFFFu) | (int)(((pk >> 17) & 3u) << 20);
    }
}

// ---- fused layer 1: gather mean(x[src])+fc into LDS, then MFMA GEMM ----
// 512 thr, 128 nodes/block. LDS: B1 32KB + means 16KB + fc 2KB.
__global__ __launch_bounds__(512, 4) void k_fused1(
    const int* __restrict__ offsets, const int* __restrict__ packed,
    const u16* __restrict__ xb, const u16* __restrict__ Bt1,
    const float* __restrict__ b1, const float* __restrict__ relp,
    u16* __restrict__ h) {
    __shared__ u16 Bs[128 * 128];   // 32KB, slot p holds chunk p^(col&7)
    __shared__ u16 Ms[128 * 64];    // 16KB means, chunk-swizzled
    __shared__ float Fs[128 * 4];   // 2KB fc
    int tid = threadIdx.x;
    int lane = tid & 63, w = tid >> 6;
    int wm = w >> 1, wn = w & 1;
    int mbase = blockIdx.x * 128;
    int r16 = lane & 15;
    int kg = (lane >> 4) * 8;
    // preload self-x A-frags (k 64..127 -> x feats 0..63), in flight during gather
    short8 xa[2][2];
    #pragma unroll
    for (int mi = 0; mi < 2; ++mi) {
        int r = min(mbase + wm * 32 + mi * 16 + r16, NN - 1);
        #pragma unroll
        for (int s = 0; s < 2; ++s)
            xa[mi][s] = *(const short8*)(xb + (size_t)r * EMB + s * 32 + kg);
    }
    // stage B
    for (int i = tid; i < 2048; i += 512) {
        int col = i >> 4, p = i & 15;
        ((short8*)Bs)[i] = *(const short8*)(Bt1 + col * 128 + ((p ^ (col & 7)) << 3));
    }
    // gather means: wave w owns nodes mbase + w*16 .. +16
    for (int it = 0; it < 16; ++it) {
        int n = mbase + w * 16 + it;
        float mean = 0.f, f0 = 0.f, f1 = 0.f, f2 = 0.f;
        if (n < NN) {
            int beg = offsets[n], end = offsets[n + 1];
            float s0 = 0.f, s1 = 0.f, s2 = 0.f, s3 = 0.f;
            int c0 = 0, c1 = 0, c2 = 0;
            int e = beg;
            for (; e + 4 <= end; e += 4) {
                int p0 = packed[e], p1 = packed[e + 1], p2 = packed[e + 2], p3 = packed[e + 3];
                s0 += bfu(xb[(p0 & 0xFFFFF) * EMB + lane]);
                s1 += bfu(xb[(p1 & 0xFFFFF) * EMB + lane]);
                s2 += bfu(xb[(p2 & 0xFFFFF) * EMB + lane]);
                s3 += bfu(xb[(p3 & 0xFFFFF) * EMB + lane]);
                int t0 = p0 >> 20, t1 = p1 >> 20, t2 = p2 >> 20, t3 = p3 >> 20;
                c0 += (t0 == 0) + (t1 == 0) + (t2 == 0) + (t3 == 0);
                c1 += (t0 == 1) + (t1 == 1) + (t2 == 1) + (t3 == 1);
                c2 += (t0 == 2) + (t1 == 2) + (t2 == 2) + (t3 == 2);
            }
            for (; e < end; ++e) {
                int p = packed[e];
                s0 += bfu(xb[(p & 0xFFFFF) * EMB + lane]);
                int t = p >> 20;
                c0 += (t == 0); c1 += (t == 1); c2 += (t == 2);
            }
            float inv = 1.0f / (float)max(end - beg, 1);
            mean = (s0 + s1 + s2 + s3) * inv;
            f0 = c0 * inv; f1 = c1 * inv; f2 = c2 * inv;
        }
        int lr = w * 16 + it;
        int byte = lr * 128 + (((lane >> 3) ^ (lr & 7)) << 4) + ((lane & 7) * 2);
        *(u16*)((char*)Ms + byte) = f2bf(mean);
        if (lane == 0) *(float4*)&Fs[lr * 4] = make_float4(f0, f1, f2, 0.f);
    }
    __syncthreads();
    f32x4 acc[2][4] = {};
    #pragma unroll
    for (int step = 0; step < 4; ++step) {
        short8 a0, a1;
        if (step < 2) {
            int c = step * 4 + (lane >> 4);
            int r0 = wm * 32 + r16;
            int r1 = r0 + 16;
            a0 = *(const short8*)((char*)Ms + r0 * 128 + ((c ^ (r0 & 7)) << 4));
            a1 = *(const short8*)((char*)Ms + r1 * 128 + ((c ^ (r1 & 7)) << 4));
        } else {
            a0 = xa[0][step - 2];
            a1 = xa[1][step - 2];
        }
        int cB = step * 4 + (lane >> 4);
        #pragma unroll
        for (int nf = 0; nf < 4; ++nf) {
            int col = wn * 64 + nf * 16 + r16;
            short8 b = ((const short8*)Bs)[col * 16 + (cB ^ (col & 7))];
            acc[0][nf] = __builtin_amdgcn_mfma_f32_16x16x32_bf16(a0, b, acc[0][nf], 0, 0, 0);
            acc[1][nf] = __builtin_amdgcn_mfma_f32_16x16x32_bf16(a1, b, acc[1][nf], 0, 0, 0);
        }
    }
    float eb[4], e0[4], e1[4], e2[4];
    #pragma unroll
    for (int nf = 0; nf < 4; ++nf) {
        int cc = wn * 64 + nf * 16 + r16;
        eb[nf] = b1[cc]; e0[nf] = relp[cc]; e1[nf] = relp[128 + cc]; e2[nf] = relp[256 + cc];
    }
    #pragma unroll
    for (int mi = 0; mi < 2; ++mi) {
        #pragma unroll
        for (int reg = 0; reg < 4; ++reg) {
            int lr = wm * 32 + mi * 16 + (lane >> 4) * 4 + reg;
            int row = mbase + lr;
            if (row >= NN) continue;
            float4 f = *(const float4*)&Fs[lr * 4];
            #pragma unroll
            for (int nf = 0; nf < 4; ++nf) {
                int cc = wn * 64 + nf * 16 + r16;
                float v = acc[mi][nf][reg] + eb[nf] + f.x * e0[nf] + f.y * e1[nf] + f.z * e2[nf];
                h[row * HID + cc] = f2bf(fmaxf(v, 0.f));
            }
        }
    }
}

// ---- fused layer 2: gather mean(h[src]) into LDS, two-phase B, MFMA, pooled max ----
// 512 thr, 128 nodes/block. LDS: B-half 32KB + means 32KB = 64KB.
__global__ __launch_bounds__(512, 4) void k_fused2(
    const int* __restrict__ offsets, const int* __restrict__ packed,
    const u16* __restrict__ h, const u16* __restrict__ Bt2,
    const float* __restrict__ b2, const int* __restrict__ batch,
    unsigned* __restrict__ genc) {
    __shared__ u16 Bs[128 * 128];   // 32KB, re-staged per K-half
    __shared__ u16 Ms[128 * 128];   // 32KB means
    int tid = threadIdx.x;
    int lane = tid & 63, w = tid >> 6;
    int wm = w >> 1, wn = w & 1;
    int mbase = blockIdx.x * 128;
    int r16 = lane & 15;
    int kg = (lane >> 4) * 8;
    // preload self-h A-frags (steps 4..7), in flight during gather
    short8 ha[2][4];
    #pragma unroll
    for (int mi = 0; mi < 2; ++mi) {
        int r = min(mbase + wm * 32 + mi * 16 + r16, NN - 1);
        #pragma unroll
        for (int s = 0; s < 4; ++s)
            ha[mi][s] = *(const short8*)(h + (size_t)r * HID + s * 32 + kg);
    }
    // stage B lo half (k 0..127)
    for (int i = tid; i < 2048; i += 512) {
        int col = i >> 4, p = i & 15;
        ((short8*)Bs)[i] = *(const short8*)(Bt2 + col * 256 + ((p ^ (col & 7)) << 3));
    }
    // gather means of h[src] (dword per lane)
    const u32* hb = (const u32*)h;
    for (int it = 0; it < 16; ++it) {
        int n = mbase + w * 16 + it;
        u32 mw = 0;
        if (n < NN) {
            int beg = offsets[n], end = offsets[n + 1];
            float a0 = 0.f, a1 = 0.f, b0 = 0.f, b1v = 0.f;
            int e = beg;
            for (; e + 2 <= end; e += 2) {
                u32 u = hb[(packed[e] & 0xFFFFF) * 64 + lane];
                u32 v = hb[(packed[e + 1] & 0xFFFFF) * 64 + lane];
                a0 += __uint_as_float(u << 16);
                a1 += __uint_as_float(u & 0xFFFF0000u);
                b0 += __uint_as_float(v << 16);
                b1v += __uint_as_float(v & 0xFFFF0000u);
            }
            if (e < end) {
                u32 u = hb[(packed[e] & 0xFFFFF) * 64 + lane];
                a0 += __uint_as_float(u << 16);
                a1 += __uint_as_float(u & 0xFFFF0000u);
            }
            float inv = 1.0f / (float)max(end - beg, 1);
            mw = (u32)f2bf((a0 + b0) * inv) | ((u32)f2bf((a1 + b1v) * inv) << 16);
        }
        int lr = w * 16 + it;
        int byte = lr * 256 + (((lane >> 2) ^ (lr & 7)) << 4) + ((lane & 3) * 4);
        *(u32*)((char*)Ms + byte) = mw;
    }
    __syncthreads();
    f32x4 acc[2][4] = {};
    #pragma unroll
    for (int step = 0; step < 4; ++step) {     // agg part: A from Ms, B lo
        int c = step * 4 + (lane >> 4);
        int r0 = wm * 32 + r16;
        int r1 = r0 + 16;
        short8 a0 = *(const short8*)((char*)Ms + r0 * 256 + ((c ^ (r0 & 7)) << 4));
        short8 a1 = *(const short8*)((char*)Ms + r1 * 256 + ((c ^ (r1 & 7)) << 4));
        #pragma unroll
        for (int nf = 0; nf < 4; ++nf) {
            int col = wn * 64 + nf * 16 + r16;
            short8 b = ((const short8*)Bs)[col * 16 + (c ^ (col & 7))];
            acc[0][nf] = __builtin_amdgcn_mfma_f32_16x16x32_bf16(a0, b, acc[0][nf], 0, 0, 0);
            acc[1][nf] = __builtin_amdgcn_mfma_f32_16x16x32_bf16(a1, b, acc[1][nf], 0, 0, 0);
        }
    }
    __syncthreads();
    // stage B hi half (k 128..255)
    for (int i = tid; i < 2048; i += 512) {
        int col = i >> 4, p = i & 15;
        ((short8*)Bs)[i] = *(const short8*)(Bt2 + col * 256 + 128 + ((p ^ (col & 7)) << 3));
    }
    __syncthreads();
    #pragma unroll
    for (int step = 0; step < 4; ++step) {     // self part: A from regs, B hi
        int c = step * 4 + (lane >> 4);
        #pragma unroll
        for (int nf = 0; nf < 4; ++nf) {
            int col = wn * 64 + nf * 16 + r16;
            short8 b = ((const short8*)Bs)[col * 16 + (c ^ (col & 7))];
            acc[0][nf] = __builtin_amdgcn_mfma_f32_16x16x32_bf16(ha[0][step], b, acc[0][nf], 0, 0, 0);
            acc[1][nf] = __builtin_amdgcn_mfma_f32_16x16x32_bf16(ha[1][step], b, acc[1][nf], 0, 0, 0);
        }
    }
    float bv[4];
    #pragma unroll
    for (int nf = 0; nf < 4; ++nf) bv[nf] = b2[wn * 64 + nf * 16 + r16];
    #pragma unroll
    for (int mi = 0; mi < 2; ++mi) {
        int r0 = mbase + wm * 32 + mi * 16 + (lane >> 4) * 4;
        if (r0 >= NN) continue;
        if (r0 + 3 < NN && batch[r0] == batch[r0 + 3]) {
            int bt = batch[r0];
            #pragma unroll
            for (int nf = 0; nf < 4; ++nf) {
                int cc = wn * 64 + nf * 16 + r16;
                f32x4 a = acc[mi][nf];
                float v = fmaxf(fmaxf(a[0], a[1]), fmaxf(a[2], a[3])) + bv[nf];
                atomicMax(&genc[bt * HID + cc], fenc(v));
            }
        } else {
            #pragma unroll
            for (int reg = 0; reg < 4; ++reg) {
                int row = r0 + reg;
                if (row >= NN) continue;
                int bt = batch[row];
                #pragma unroll
                for (int nf = 0; nf < 4; ++nf) {
                    int cc = wn * 64 + nf * 16 + r16;
                    atomicMax(&genc[bt * HID + cc], fenc(acc[mi][nf][reg] + bv[nf]));
                }
            }
        }
    }
}

__global__ void k_final(const unsigned* __restrict__ genc,
                        const float* __restrict__ lin_w, const float* __restrict__ lin_b,
                        float* __restrict__ out) {
    int gr = blockIdx.x;
    int lane = threadIdx.x;  // 64
    float g0 = fmaxf(fdec(genc[gr * HID + lane]), 0.f);
    float g1 = fmaxf(fdec(genc[gr * HID + 64 + lane]), 0.f);
    #pragma unroll
    for (int c = 0; c < NCLS; ++c) {
        float p = g0 * lin_w[lane * NCLS + c] + g1 * lin_w[(lane + 64) * NCLS + c];
        for (int off = 32; off > 0; off >>= 1)
            p += __shfl_down(p, off, 64);
        if (lane == 0) out[gr * NCLS + c] = p + lin_b[c];
    }
}

extern "C" void kernel_launch(void* const* d_in, const int* in_sizes, int n_in,
                              void* d_out, int out_size, void* d_ws, size_t ws_size,
                              hipStream_t stream) {
    const int* x_tokens   = (const int*)d_in[0];
    const int* edge_index = (const int*)d_in[1];
    const int* edge_type  = (const int*)d_in[2];
    const int* batch      = (const int*)d_in[3];
    const float* emb_table = (const float*)d_in[5];
    const float* rel_table = (const float*)d_in[6];
    const float* w1_l = (const float*)d_in[7];
    const float* b1   = (const float*)d_in[8];
    const float* w1_r = (const float*)d_in[9];
    const float* w2_l = (const float*)d_in[10];
    const float* b2   = (const float*)d_in[11];
    const float* w2_r = (const float*)d_in[12];
    const float* lin_w = (const float*)d_in[13];
    const float* lin_b = (const float*)d_in[14];
    float* out = (float*)d_out;

    const int* src = edge_index;
    const int* dst = edge_index + NE;

    char* ws = (char*)d_ws;
    size_t off = 0;
    auto alloc = [&](size_t bytes) {
        void* p = ws + off;
        off = (off + bytes + 255) & ~(size_t)255;
        return p;
    };
    u16* xb      = (u16*)alloc((size_t)NN * EMB * 2);    // 12.8 MB
    u16* h       = (u16*)alloc((size_t)NN * HID * 2);    // 25.6 MB
    int* offsets = (int*)alloc((size_t)(NN + 1) * 4);
    int* packed  = (int*)alloc((size_t)NE * 4);
    u32* coarse  = (u32*)alloc((size_t)NE * 4);
    int* counts  = (int*)alloc((size_t)NSCAN * 4);
    int* scanned = (int*)alloc((size_t)NSCAN * 4);
    int* gpart   = (int*)alloc((size_t)128 * 4);
    unsigned* genc = (unsigned*)alloc((size_t)NG * HID * 4);
    float* relp  = (float*)alloc((size_t)3 * HID * 4);
    u16* Bt1     = (u16*)alloc((size_t)128 * 128 * 2);
    u16* Bt2     = (u16*)alloc((size_t)128 * 256 * 2);
    (void)ws_size; (void)in_sizes; (void)n_in; (void)out_size;

    const int MT = (NN + 127) / 128;  // 782 fused tiles

    hipLaunchKernelGGL(k_init,   dim3(1000), dim3(256), 0, stream,
                       genc, relp, Bt1, Bt2, rel_table, w1_l, w1_r, w2_l, w2_r);
    hipLaunchKernelGGL(k_embed,  dim3(NN * 32 / 256), dim3(256), 0, stream,
                       x_tokens, emb_table, (u32*)xb);
    hipLaunchKernelGGL(k_cnt,    dim3(NBA), dim3(256), 0, stream, dst, counts);
    hipLaunchKernelGGL(k_gs1,    dim3(GS_NB), dim3(256), 0, stream, counts, gpart);
    hipLaunchKernelGGL(k_gs2,    dim3(1), dim3(128), 0, stream, gpart);
    hipLaunchKernelGGL(k_gs3,    dim3(GS_NB), dim3(256), 0, stream, counts, gpart, scanned);
    hipLaunchKernelGGL(k_part,   dim3(NBA), dim3(256), 0, stream,
                       src, dst, edge_type, scanned, coarse);
    hipLaunchKernelGGL(k_csr,    dim3(NBKT), dim3(256), 0, stream,
                       scanned, coarse, offsets, packed);
    hipLaunchKernelGGL(k_fused1, dim3(MT), dim3(512), 0, stream,
                       offsets, packed, xb, Bt1, b1, relp, h);
    hipLaunchKernelGGL(k_fused2, dim3(MT), dim3(512), 0, stream,
                       offsets, packed, h, Bt2, b2, batch, genc);
    hipLaunchKernelGGL(k_final,  dim3(NG), dim3(64), 0, stream, genc, lin_w, lin_b, out);
}

// Round 7
// 195.779 us; speedup vs baseline: 1.4453x; 1.4453x over previous
//
#include <hip/hip_runtime.h>
#include <hip/hip_bf16.h>

#define NN 100000
#define NE 800000
#define NG 2000
#define EMB 64
#define HID 128
#define NCLS 10

#define NBKT 196                       // coarse dst buckets (512 nodes each)
#define EPB 4096                       // edges per counting block
#define NBA ((NE + EPB - 1) / EPB)     // 196 counting blocks
#define NSCAN (NBKT * NBA)             // 38416
#define GS_NB ((NSCAN + 511) / 512)    // 76

typedef __attribute__((ext_vector_type(8))) short short8;
typedef __attribute__((ext_vector_type(4))) float f32x4;
typedef unsigned short u16;
typedef unsigned int u32;

// monotone float<->uint encoding so unsigned atomicMax == float max
static __device__ __forceinline__ unsigned fenc(float f) {
    unsigned u = __float_as_uint(f);
    return (u & 0x80000000u) ? ~u : (u | 0x80000000u);
}
static __device__ __forceinline__ float fdec(unsigned u) {
    return (u & 0x80000000u) ? __uint_as_float(u & 0x7FFFFFFFu) : __uint_as_float(~u);
}
static __device__ __forceinline__ u16 f2bf(float f) {
    u32 u = __float_as_uint(f);
    return (u16)((u + 0x7FFFu + ((u >> 16) & 1u)) >> 16);
}

__global__ void k_init(unsigned* genc, float* relp, u16* Bt1, u16* Bt2,
                       const float* rel_table, const float* w1l, const float* w1r,
                       const float* w2l, const float* w2r) {
    int i = blockIdx.x * 256 + threadIdx.x;   // grid covers 256000
    if (i < NG * HID) genc[i] = 0x007FFFFFu;  // fenc(-inf)
    if (i < 3 * HID) {
        int t = i >> 7, j = i & 127;
        float s = 0.f;
        for (int k = 0; k < 16; ++k)
            s += rel_table[t * 16 + k] * w1l[(64 + k) * HID + j];
        relp[i] = s;
    }
    if (i < 128 * 128) {   // Bt1[c][k] = B1[k][c], B1 = [w1l[0:64]; w1r]
        int c = i >> 7, k = i & 127;
        float w = (k < 64) ? w1l[k * HID + c] : w1r[(k - 64) * HID + c];
        Bt1[c * 128 + k] = f2bf(w);
    }
    if (i < 128 * 256) {   // Bt2[c][k] = B2[k][c], B2 = [w2l; w2r]
        int c = i >> 8, k = i & 255;
        float w = (k < 128) ? w2l[k * HID + c] : w2r[(k - 128) * HID + c];
        Bt2[c * 256 + k] = f2bf(w);
    }
}

// embedding gather -> bf16 x [NN][64]; thread handles 2 features
__global__ void k_embed(const int* __restrict__ tok, const float* __restrict__ emb,
                        u32* __restrict__ xb) {
    int i = blockIdx.x * 256 + threadIdx.x;   // < NN*32
    int n = i >> 5, p = i & 31;
    float2 e = *(const float2*)&emb[tok[n] * EMB + p * 2];
    xb[i] = (u32)f2bf(e.x) | ((u32)f2bf(e.y) << 16);
}

// ---- atomic-free CSR build: two-level counting sort by dst ----

__global__ __launch_bounds__(256) void k_cnt(const int* __restrict__ dst,
                                             int* __restrict__ counts) {
    __shared__ int hist[NBKT];
    int t = threadIdx.x;
    for (int i = t; i < NBKT; i += 256) hist[i] = 0;
    __syncthreads();
    int base = blockIdx.x * EPB;
    for (int j = t; j < EPB; j += 256) {
        int e = base + j;
        if (e < NE) atomicAdd(&hist[dst[e] >> 9], 1);
    }
    __syncthreads();
    for (int i = t; i < NBKT; i += 256)
        counts[i * NBA + blockIdx.x] = hist[i];  // bucket-major for scan
}

__global__ __launch_bounds__(256) void k_gs1(const int* __restrict__ v, int* __restrict__ part) {
    __shared__ int ws[4];
    int t = threadIdx.x;
    int i0 = blockIdx.x * 512 + t * 2;
    int e0 = (i0 < NSCAN) ? v[i0] : 0;
    int e1 = (i0 + 1 < NSCAN) ? v[i0 + 1] : 0;
    int s = e0 + e1;
    for (int off = 32; off > 0; off >>= 1) s += __shfl_down(s, off, 64);
    if ((t & 63) == 0) ws[t >> 6] = s;
    __syncthreads();
    if (t == 0) part[blockIdx.x] = ws[0] + ws[1] + ws[2] + ws[3];
}

__global__ __launch_bounds__(128) void k_gs2(int* __restrict__ part) {
    __shared__ int s[128];
    int t = threadIdx.x;
    int v = (t < GS_NB) ? part[t] : 0;
    s[t] = v;
    __syncthreads();
    for (int off = 1; off < 128; off <<= 1) {
        int u = (t >= off) ? s[t - off] : 0;
        __syncthreads();
        s[t] += u;
        __syncthreads();
    }
    if (t < GS_NB) part[t] = s[t] - v;  // exclusive
}

__global__ __launch_bounds__(256) void k_gs3(const int* __restrict__ v,
                                             const int* __restrict__ part,
                                             int* __restrict__ out) {
    __shared__ int s[256];
    int t = threadIdx.x;
    int i0 = blockIdx.x * 512 + t * 2;
    int e0 = (i0 < NSCAN) ? v[i0] : 0;
    int e1 = (i0 + 1 < NSCAN) ? v[i0 + 1] : 0;
    int tsum = e0 + e1;
    s[t] = tsum;
    __syncthreads();
    for (int off = 1; off < 256; off <<= 1) {
        int u = (t >= off) ? s[t - off] : 0;
        __syncthreads();
        s[t] += u;
        __syncthreads();
    }
    int p0 = part[blockIdx.x] + s[t] - tsum;
    if (i0 < NSCAN) out[i0] = p0;
    if (i0 + 1 < NSCAN) out[i0 + 1] = p0 + e0;
}

// pack: src(17) | etype(2)<<17 | dstlow(9)<<19
__global__ __launch_bounds__(256) void k_part(const int* __restrict__ src,
                                              const int* __restrict__ dst,
                                              const int* __restrict__ et,
                                              const int* __restrict__ scanned,
                                              u32* __restrict__ coarse) {
    __shared__ int cur[NBKT];
    int t = threadIdx.x;
    for (int i = t; i < NBKT; i += 256) cur[i] = scanned[i * NBA + blockIdx.x];
    __syncthreads();
    int base = blockIdx.x * EPB;
    for (int j = t; j < EPB; j += 256) {
        int e = base + j;
        if (e < NE) {
            int d = dst[e];
            int pos = atomicAdd(&cur[d >> 9], 1);
            coarse[pos] = (u32)src[e] | ((u32)et[e] << 17) | ((u32)(d & 511) << 19);
        }
    }
}

__global__ __launch_bounds__(256) void k_csr(const int* __restrict__ scanned,
                                             const u32* __restrict__ coarse,
                                             int* __restrict__ offsets,
                                             int* __restrict__ packed) {
    __shared__ int hist[512];
    __shared__ int ex[512];
    __shared__ int ts[256];
    int b = blockIdx.x, t = threadIdx.x;
    int beg = scanned[b * NBA];
    int end = (b + 1 < NBKT) ? scanned[(b + 1) * NBA] : NE;
    hist[t] = 0; hist[t + 256] = 0;
    __syncthreads();
    for (int i = beg + t; i < end; i += 256)
        atomicAdd(&hist[(coarse[i] >> 19) & 511], 1);
    __syncthreads();
    int a0 = hist[2 * t], a1 = hist[2 * t + 1];
    int sum = a0 + a1;
    ts[t] = sum;
    __syncthreads();
    for (int off = 1; off < 256; off <<= 1) {
        int u = (t >= off) ? ts[t - off] : 0;
        __syncthreads();
        ts[t] += u;
        __syncthreads();
    }
    int ep = ts[t] - sum;
    ex[2 * t] = ep;
    ex[2 * t + 1] = ep + a0;
    __syncthreads();
    int node0 = b * 512;
    if (node0 + 2 * t < NN)     offsets[node0 + 2 * t]     = beg + ex[2 * t];
    if (node0 + 2 * t + 1 < NN) offsets[node0 + 2 * t + 1] = beg + ex[2 * t + 1];
    if (b == NBKT - 1 && t == 0) offsets[NN] = NE;
    hist[2 * t] = beg + ex[2 * t];
    hist[2 * t + 1] = beg + ex[2 * t + 1];
    __syncthreads();
    for (int i = beg + t; i < end; i += 256) {
        u32 pk = coarse[i];
        int pos = atomicAdd(&hist[(pk >> 19) & 511], 1);
        packed[pos] = (int)(pk & 0x1FFFFu) | (int)(((pk >> 17) & 3u) << 20);
    }
}

// gather: mean of x[src] + relation-type fractions. One wave per node.
// Lane-parallel edge-index prefetch (one coalesced load per 64 edges, shfl broadcast);
// lanes 0-31 process even edges, 32-63 odd edges (256B per load instruction).
__global__ __launch_bounds__(256) void k_agg1(
    const int* __restrict__ offsets, const int* __restrict__ packed,
    const u32* __restrict__ xw, u32* __restrict__ aggx, float* __restrict__ fc) {
    int node = (blockIdx.x * 256 + threadIdx.x) >> 6;
    int lane = threadIdx.x & 63;
    int half = lane >> 5;
    int fl = lane & 31;
    int beg = offsets[node], end = offsets[node + 1];
    float a0 = 0.f, a1 = 0.f;
    int c0 = 0, c1 = 0, c2 = 0;
    for (int cb = beg; cb < end; cb += 64) {
        int pk = packed[min(cb + lane, NE - 1)];
        int cnt = min(end - cb, 64);
        int j = 0;
        for (; j + 8 <= cnt; j += 8) {
            #pragma unroll
            for (int q = 0; q < 4; ++q) {
                int p = __shfl(pk, j + q * 2 + half, 64);
                u32 v = xw[(p & 0xFFFFF) * 32 + fl];
                a0 += __uint_as_float(v << 16);
                a1 += __uint_as_float(v & 0xFFFF0000u);
                int t = p >> 20;
                c0 += (t == 0); c1 += (t == 1); c2 += (t == 2);
            }
        }
        for (; j < cnt; j += 2) {
            int idx = j + half;
            if (idx < cnt) {
                int p = __shfl(pk, idx, 64);
                u32 v = xw[(p & 0xFFFFF) * 32 + fl];
                a0 += __uint_as_float(v << 16);
                a1 += __uint_as_float(v & 0xFFFF0000u);
                int t = p >> 20;
                c0 += (t == 0); c1 += (t == 1); c2 += (t == 2);
            }
        }
    }
    // merge the two half-wave partial sums
    a0 += __shfl_xor(a0, 32, 64);
    a1 += __shfl_xor(a1, 32, 64);
    c0 += __shfl_xor(c0, 32, 64);
    c1 += __shfl_xor(c1, 32, 64);
    c2 += __shfl_xor(c2, 32, 64);
    float inv = 1.0f / (float)max(end - beg, 1);
    if (half == 0)
        aggx[node * 32 + fl] = (u32)f2bf(a0 * inv) | ((u32)f2bf(a1 * inv) << 16);
    if (lane == 0)
        *(float4*)&fc[node * 4] = make_float4(c0 * inv, c1 * inv, c2 * inv, 0.f);
}

// gather: mean of h[src] (128 bf16 = 64 dwords = full wave). One wave per node.
__global__ __launch_bounds__(256) void k_agg2(
    const int* __restrict__ offsets, const int* __restrict__ packed,
    const u32* __restrict__ hb, u32* __restrict__ aggh) {
    int node = (blockIdx.x * 256 + threadIdx.x) >> 6;
    int lane = threadIdx.x & 63;
    int beg = offsets[node], end = offsets[node + 1];
    float a0 = 0.f, a1 = 0.f;
    for (int cb = beg; cb < end; cb += 64) {
        int pk = packed[min(cb + lane, NE - 1)] & 0xFFFFF;
        int cnt = min(end - cb, 64);
        int j = 0;
        for (; j + 4 <= cnt; j += 4) {
            int s0 = __shfl(pk, j, 64), s1 = __shfl(pk, j + 1, 64);
            int s2 = __shfl(pk, j + 2, 64), s3 = __shfl(pk, j + 3, 64);
            u32 u0 = hb[(size_t)s0 * 64 + lane];
            u32 u1 = hb[(size_t)s1 * 64 + lane];
            u32 u2 = hb[(size_t)s2 * 64 + lane];
            u32 u3 = hb[(size_t)s3 * 64 + lane];
            a0 += __uint_as_float(u0 << 16) + __uint_as_float(u1 << 16)
                + __uint_as_float(u2 << 16) + __uint_as_float(u3 << 16);
            a1 += __uint_as_float(u0 & 0xFFFF0000u) + __uint_as_float(u1 & 0xFFFF0000u)
                + __uint_as_float(u2 & 0xFFFF0000u) + __uint_as_float(u3 & 0xFFFF0000u);
        }
        for (; j < cnt; ++j) {
            u32 u = hb[(size_t)__shfl(pk, j, 64) * 64 + lane];
            a0 += __uint_as_float(u << 16);
            a1 += __uint_as_float(u & 0xFFFF0000u);
        }
    }
    float inv = 1.0f / (float)max(end - beg, 1);
    aggh[node * 64 + lane] = (u32)f2bf(a0 * inv) | ((u32)f2bf(a1 * inv) << 16);
}

// MFMA GEMM layer1: M=128/block (512 thr, 8 waves), K=128, B in swizzled LDS.
__global__ __launch_bounds__(512) void k_gemm1(
    const u16* __restrict__ aggx, const u16* __restrict__ xb,
    const float* __restrict__ fc, const u16* __restrict__ Bt1,
    const float* __restrict__ b1, const float* __restrict__ relp,
    u16* __restrict__ h) {
    __shared__ u16 Bs[128 * 128];   // 32KB; slot p holds canonical chunk p^(col&7)
    int tid = threadIdx.x;
    for (int i = tid; i < 2048; i += 512) {
        int col = i >> 4, p = i & 15;
        ((short8*)Bs)[i] = *(const short8*)(Bt1 + col * 128 + ((p ^ (col & 7)) << 3));
    }
    int lane = tid & 63, w = tid >> 6;
    int wm = w >> 1, wn = w & 1;
    int mbase = blockIdx.x * 128 + wm * 32;
    int ra = min(mbase + (lane & 15), NN - 1);
    int rb = min(mbase + 16 + (lane & 15), NN - 1);
    int kg = (lane >> 4) * 8;
    f32x4 acc[2][4] = {};
    __syncthreads();
    #pragma unroll
    for (int step = 0; step < 4; ++step) {
        int kk = step * 32 + kg;
        const u16* pa = (step < 2) ? (aggx + ra * EMB + kk) : (xb + ra * EMB + kk - 64);
        const u16* pb = (step < 2) ? (aggx + rb * EMB + kk) : (xb + rb * EMB + kk - 64);
        short8 a0 = *(const short8*)pa;
        short8 a1 = *(const short8*)pb;
        int c = step * 4 + (lane >> 4);
        #pragma unroll
        for (int nf = 0; nf < 4; ++nf) {
            int col = wn * 64 + nf * 16 + (lane & 15);
            short8 b = *(const short8*)&Bs[col * 128 + ((c ^ (col & 7)) << 3)];
            acc[0][nf] = __builtin_amdgcn_mfma_f32_16x16x32_bf16(a0, b, acc[0][nf], 0, 0, 0);
            acc[1][nf] = __builtin_amdgcn_mfma_f32_16x16x32_bf16(a1, b, acc[1][nf], 0, 0, 0);
        }
    }
    float eb[4], e0[4], e1[4], e2[4];
    #pragma unroll
    for (int nf = 0; nf < 4; ++nf) {
        int cc = wn * 64 + nf * 16 + (lane & 15);
        eb[nf] = b1[cc]; e0[nf] = relp[cc]; e1[nf] = relp[128 + cc]; e2[nf] = relp[256 + cc];
    }
    #pragma unroll
    for (int mi = 0; mi < 2; ++mi) {
        #pragma unroll
        for (int reg = 0; reg < 4; ++reg) {
            int row = mbase + mi * 16 + (lane >> 4) * 4 + reg;
            if (row >= NN) continue;
            float4 f = *(const float4*)&fc[row * 4];
            #pragma unroll
            for (int nf = 0; nf < 4; ++nf) {
                int cc = wn * 64 + nf * 16 + (lane & 15);
                float v = acc[mi][nf][reg] + eb[nf] + f.x * e0[nf] + f.y * e1[nf] + f.z * e2[nf];
                h[row * HID + cc] = f2bf(fmaxf(v, 0.f));
            }
        }
    }
}

// MFMA GEMM layer2: M=128/block (512 thr), K=256, B in swizzled LDS; pooled atomicMax
__global__ __launch_bounds__(512) void k_gemm2(
    const u16* __restrict__ aggh, const u16* __restrict__ h,
    const u16* __restrict__ Bt2, const float* __restrict__ b2,
    const int* __restrict__ batch, unsigned* __restrict__ genc) {
    __shared__ u16 Bs[128 * 256];   // 64KB
    int tid = threadIdx.x;
    for (int i = tid; i < 4096; i += 512) {
        int col = i >> 5, p = i & 31;
        ((short8*)Bs)[i] = *(const short8*)(Bt2 + col * 256 + ((p ^ (col & 7)) << 3));
    }
    int lane = tid & 63, w = tid >> 6;
    int wm = w >> 1, wn = w & 1;
    int mbase = blockIdx.x * 128 + wm * 32;
    int ra = min(mbase + (lane & 15), NN - 1);
    int rb = min(mbase + 16 + (lane & 15), NN - 1);
    int kg = (lane >> 4) * 8;
    f32x4 acc[2][4] = {};
    __syncthreads();
    #pragma unroll
    for (int step = 0; step < 8; ++step) {
        int kk = step * 32 + kg;
        const u16* pa = (step < 4) ? (aggh + ra * HID + kk) : (h + ra * HID + kk - 128);
        const u16* pb = (step < 4) ? (aggh + rb * HID + kk) : (h + rb * HID + kk - 128);
        short8 a0 = *(const short8*)pa;
        short8 a1 = *(const short8*)pb;
        int c = step * 4 + (lane >> 4);
        #pragma unroll
        for (int nf = 0; nf < 4; ++nf) {
            int col = wn * 64 + nf * 16 + (lane & 15);
            short8 b = *(const short8*)&Bs[col * 256 + ((c ^ (col & 7)) << 3)];
            acc[0][nf] = __builtin_amdgcn_mfma_f32_16x16x32_bf16(a0, b, acc[0][nf], 0, 0, 0);
            acc[1][nf] = __builtin_amdgcn_mfma_f32_16x16x32_bf16(a1, b, acc[1][nf], 0, 0, 0);
        }
    }
    float bv[4];
    #pragma unroll
    for (int nf = 0; nf < 4; ++nf) bv[nf] = b2[wn * 64 + nf * 16 + (lane & 15)];
    #pragma unroll
    for (int mi = 0; mi < 2; ++mi) {
        int r0 = mbase + mi * 16 + (lane >> 4) * 4;
        if (r0 >= NN) continue;
        if (r0 + 3 < NN && batch[r0] == batch[r0 + 3]) {
            int bt = batch[r0];
            #pragma unroll
            for (int nf = 0; nf < 4; ++nf) {
                int cc = wn * 64 + nf * 16 + (lane & 15);
                f32x4 a = acc[mi][nf];
                float v = fmaxf(fmaxf(a[0], a[1]), fmaxf(a[2], a[3])) + bv[nf];
                atomicMax(&genc[bt * HID + cc], fenc(v));
            }
        } else {
            #pragma unroll
            for (int reg = 0; reg < 4; ++reg) {
                int row = r0 + reg;
                if (row >= NN) continue;
                int bt = batch[row];
                #pragma unroll
                for (int nf = 0; nf < 4; ++nf) {
                    int cc = wn * 64 + nf * 16 + (lane & 15);
                    atomicMax(&genc[bt * HID + cc], fenc(acc[mi][nf][reg] + bv[nf]));
                }
            }
        }
    }
}

__global__ void k_final(const unsigned* __restrict__ genc,
                        const float* __restrict__ lin_w, const float* __restrict__ lin_b,
                        float* __restrict__ out) {
    int gr = blockIdx.x;
    int lane = threadIdx.x;  // 64
    float g0 = fmaxf(fdec(genc[gr * HID + lane]), 0.f);
    float g1 = fmaxf(fdec(genc[gr * HID + 64 + lane]), 0.f);
    #pragma unroll
    for (int c = 0; c < NCLS; ++c) {
        float p = g0 * lin_w[lane * NCLS + c] + g1 * lin_w[(lane + 64) * NCLS + c];
        for (int off = 32; off > 0; off >>= 1)
            p += __shfl_down(p, off, 64);
        if (lane == 0) out[gr * NCLS + c] = p + lin_b[c];
    }
}

extern "C" void kernel_launch(void* const* d_in, const int* in_sizes, int n_in,
                              void* d_out, int out_size, void* d_ws, size_t ws_size,
                              hipStream_t stream) {
    const int* x_tokens   = (const int*)d_in[0];
    const int* edge_index = (const int*)d_in[1];
    const int* edge_type  = (const int*)d_in[2];
    const int* batch      = (const int*)d_in[3];
    const float* emb_table = (const float*)d_in[5];
    const float* rel_table = (const float*)d_in[6];
    const float* w1_l = (const float*)d_in[7];
    const float* b1   = (const float*)d_in[8];
    const float* w1_r = (const float*)d_in[9];
    const float* w2_l = (const float*)d_in[10];
    const float* b2   = (const float*)d_in[11];
    const float* w2_r = (const float*)d_in[12];
    const float* lin_w = (const float*)d_in[13];
    const float* lin_b = (const float*)d_in[14];
    float* out = (float*)d_out;

    const int* src = edge_index;
    const int* dst = edge_index + NE;

    char* ws = (char*)d_ws;
    size_t off = 0;
    auto alloc = [&](size_t bytes) {
        void* p = ws + off;
        off = (off + bytes + 255) & ~(size_t)255;
        return p;
    };
    u16* xb      = (u16*)alloc((size_t)NN * EMB * 2);    // 12.8 MB
    u16* aggx    = (u16*)alloc((size_t)NN * EMB * 2);    // 12.8 MB
    u16* h       = (u16*)alloc((size_t)NN * HID * 2);    // 25.6 MB
    u16* aggh    = (u16*)alloc((size_t)NN * HID * 2);    // 25.6 MB
    float* fc    = (float*)alloc((size_t)NN * 4 * 4);
    int* offsets = (int*)alloc((size_t)(NN + 1) * 4);
    int* packed  = (int*)alloc((size_t)NE * 4);
    u32* coarse  = (u32*)alloc((size_t)NE * 4);
    int* counts  = (int*)alloc((size_t)NSCAN * 4);
    int* scanned = (int*)alloc((size_t)NSCAN * 4);
    int* gpart   = (int*)alloc((size_t)128 * 4);
    unsigned* genc = (unsigned*)alloc((size_t)NG * HID * 4);
    float* relp  = (float*)alloc((size_t)3 * HID * 4);
    u16* Bt1     = (u16*)alloc((size_t)128 * 128 * 2);
    u16* Bt2     = (u16*)alloc((size_t)128 * 256 * 2);
    (void)ws_size; (void)in_sizes; (void)n_in; (void)out_size;

    const int MT = (NN + 127) / 128;  // 782 GEMM m-tiles

    hipLaunchKernelGGL(k_init,  dim3(1000), dim3(256), 0, stream,
                       genc, relp, Bt1, Bt2, rel_table, w1_l, w1_r, w2_l, w2_r);
    hipLaunchKernelGGL(k_embed, dim3(NN * 32 / 256), dim3(256), 0, stream,
                       x_tokens, emb_table, (u32*)xb);
    hipLaunchKernelGGL(k_cnt,   dim3(NBA), dim3(256), 0, stream, dst, counts);
    hipLaunchKernelGGL(k_gs1,   dim3(GS_NB), dim3(256), 0, stream, counts, gpart);
    hipLaunchKernelGGL(k_gs2,   dim3(1), dim3(128), 0, stream, gpart);
    hipLaunchKernelGGL(k_gs3,   dim3(GS_NB), dim3(256), 0, stream, counts, gpart, scanned);
    hipLaunchKernelGGL(k_part,  dim3(NBA), dim3(256), 0, stream,
                       src, dst, edge_type, scanned, coarse);
    hipLaunchKernelGGL(k_csr,   dim3(NBKT), dim3(256), 0, stream,
                       scanned, coarse, offsets, packed);
    hipLaunchKernelGGL(k_agg1,  dim3(NN / 4), dim3(256), 0, stream,
                       offsets, packed, (const u32*)xb, (u32*)aggx, fc);
    hipLaunchKernelGGL(k_gemm1, dim3(MT), dim3(512), 0, stream,
                       aggx, xb, fc, Bt1, b1, relp, h);
    hipLaunchKernelGGL(k_agg2,  dim3(NN / 4), dim3(256), 0, stream,
                       offsets, packed, (const u32*)h, (u32*)aggh);
    hipLaunchKernelGGL(k_gemm2, dim3(MT), dim3(512), 0, stream,
                       aggh, h, Bt2, b2, batch, genc);
    hipLaunchKernelGGL(k_final, dim3(NG), dim3(64), 0, stream, genc, lin_w, lin_b, out);
}